// Round 6
// baseline (1087.949 us; speedup 1.0000x reference)
//
#include <hip/hip_runtime.h>

constexpr int D = 64;
constexpr int NREL = 2;
constexpr int NBASIS = 16;
constexpr int NLAYERS = 3;
constexpr int BSH = 7;              // bucket = dst >> 7 (128 nodes/bucket)
constexpr int BNODES = 1 << BSH;    // 128
constexpr int TR = 32;              // rows per node-kernel tile

// h_r = alpha @ Basis   -> hr[3][64]
__global__ void hr_init_kernel(const float* __restrict__ alpha,
                               const float* __restrict__ basis,
                               float* __restrict__ hr) {
  int t = threadIdx.x;            // 192 threads
  int r = t >> 6, d = t & 63;
  float s = 0.f;
  for (int b = 0; b < NBASIS; ++b) s += alpha[r * NBASIS + b] * basis[b * D + d];
  hr[r * D + d] = s;
}

// h_r = act(h_r @ W_rel.T)
__global__ void hr_update_kernel(const float* __restrict__ hr_in,
                                 const float* __restrict__ Wrel,
                                 float* __restrict__ hr_out, int do_relu) {
  int t = threadIdx.x;            // 192 threads
  int r = t >> 6, d = t & 63;
  float s = 0.f;
  for (int k = 0; k < D; ++k) s += hr_in[r * D + k] * Wrel[d * D + k];
  if (do_relu) s = fmaxf(s, 0.f);
  hr_out[r * D + d] = s;
}

// ---- two-level bucket CSR build ----
// K1: coarse histogram (782 hot counters, L2-resident)
__global__ void bucket_hist(const int* __restrict__ dst, int* __restrict__ bcnt, int E) {
  int e = blockIdx.x * blockDim.x + threadIdx.x;
  if (e < E) atomicAdd(&bcnt[dst[e] >> BSH], 1);
}

// K2: single-block scan of bucket counts (NB <= 1024). bstart[NB] = E.
__global__ void bucket_scan(const int* __restrict__ bcnt, int* __restrict__ bstart,
                            int* __restrict__ bcursor, int NB) {
  __shared__ int sh[1024];
  int t = threadIdx.x;
  int v = (t < NB) ? bcnt[t] : 0;
  sh[t] = v;
  __syncthreads();
  for (int off = 1; off < 1024; off <<= 1) {
    int u = (t >= off) ? sh[t - off] : 0;
    __syncthreads();
    sh[t] += u;
    __syncthreads();
  }
  if (t < NB) {
    int excl = sh[t] - v;
    bstart[t] = excl;
    bcursor[t] = excl;
  }
  if (t == NB - 1) bstart[NB] = sh[t];
}

// K3: scatter edges into contiguous bucket regions (782 active regions -> good locality)
// payload: src[0:16] | et<<17 | dir<<18 | dstlow<<19  (26 bits)
__global__ void bucket_scatter(const int* __restrict__ src, const int* __restrict__ dst,
                               const int* __restrict__ et, const int* __restrict__ dir,
                               int* __restrict__ bcursor, int* __restrict__ tmp, int E) {
  int e = blockIdx.x * blockDim.x + threadIdx.x;
  if (e < E) {
    int d = dst[e];
    int b = d >> BSH;
    int p = atomicAdd(&bcursor[b], 1);
    tmp[p] = src[e] | (et[e] << 17) | (dir[e] << 18) | ((d & (BNODES - 1)) << 19);
  }
}

// K4: one block per bucket: LDS histogram over 128 local nodes, LDS scan
// (produces startv directly -- no N-wide scan needed), then write perm into the
// bucket's contiguous region (~6KB -> no cache thrash).
__global__ __launch_bounds__(256) void bucket_finalize(
    const int* __restrict__ tmp, const int* __restrict__ bstart,
    int* __restrict__ startv, int* __restrict__ perm, int N, int NB) {
  int b = blockIdx.x;
  int beg = bstart[b], end = bstart[b + 1];
  __shared__ int lcnt[BNODES];
  __shared__ int lpre[BNODES];
  __shared__ int lcur[BNODES];
  int t = threadIdx.x;
  if (t < BNODES) lcnt[t] = 0;
  __syncthreads();
  for (int j = beg + t; j < end; j += 256)
    atomicAdd(&lcnt[(tmp[j] >> 19) & (BNODES - 1)], 1);
  __syncthreads();
  if (t < BNODES) lpre[t] = lcnt[t];
  __syncthreads();
  for (int off = 1; off < BNODES; off <<= 1) {
    int u = 0;
    if (t < BNODES && t >= off) u = lpre[t - off];
    __syncthreads();
    if (t < BNODES) lpre[t] += u;
    __syncthreads();
  }
  if (t < BNODES) {
    int excl = lpre[t] - lcnt[t];
    lcur[t] = excl;
    int v = (b << BSH) + t;
    if (v < N) startv[v] = beg + excl;
  }
  if (b == NB - 1 && t == 0) startv[N] = end;   // == E
  __syncthreads();
  for (int j = beg + t; j < end; j += 256) {
    int w = tmp[j];
    int p = atomicAdd(&lcur[(w >> 19) & (BNODES - 1)], 1);
    perm[beg + p] = w & 0x7FFFF;
  }
}

// wave per node: aggO[v], aggI[v] = sum over in-edges of (h[src]-hr[et]) split by dir.
// Edges processed in masked groups of 8: 8 independent row loads in flight
// (8-deep MLP breaks the serial load->add chain; masked slots re-load a cached row).
__global__ __launch_bounds__(256) void gather_kernel(
    const float* __restrict__ h, const float* __restrict__ hr,
    const int* __restrict__ start, const int* __restrict__ perm,
    float* __restrict__ aggO, float* __restrict__ aggI, int N) {
  int lane = threadIdx.x & 63;
  int v = blockIdx.x * 4 + (threadIdx.x >> 6);
  if (v >= N) return;
  float hr0 = hr[lane];
  float hr1 = hr[D + lane];
  int beg = start[v], end = start[v + 1];
  float accO = 0.f, accI = 0.f;
  for (int j = beg; j < end; j += 8) {
    int pp[8];
    float ff[8];
#pragma unroll
    for (int u = 0; u < 8; ++u) {
      int jj = j + u < end ? j + u : beg;   // OOB clamps to beg (cached)
      pp[u] = perm[jj];
    }
#pragma unroll
    for (int u = 0; u < 8; ++u)
      ff[u] = h[(size_t)(pp[u] & 0x1FFFF) * D + lane];
#pragma unroll
    for (int u = 0; u < 8; ++u) {
      if (j + u < end) {
        float c = ff[u] - (((pp[u] >> 17) & 1) ? hr1 : hr0);
        if (pp[u] & (1 << 18)) accI += c; else accO += c;
      }
    }
  }
  aggO[(size_t)v * D + lane] = accO;
  aggI[(size_t)v * D + lane] = accI;
}

// h_out[v] = act((h[v]-hr_self)@WS.T + aggO[v]@WO.T + aggI[v]@WI.T)
// Tile of TR=32 rows staged in LDS (coalesced float4, -hr_self fused into xh);
// compute reads x via same-address LDS broadcast, W via pad-17 layout (conflict-free).
__global__ __launch_bounds__(256, 2) void node_kernel(
    const float* __restrict__ h_in, const float* __restrict__ aggO,
    const float* __restrict__ aggI, const float* __restrict__ WS,
    const float* __restrict__ WO, const float* __restrict__ WI,
    const float* __restrict__ hr_self, float* __restrict__ h_out,
    int do_relu, int N, int ntiles) {
  __shared__ float4 lws[64 * 17];
  __shared__ float4 lwo[64 * 17];
  __shared__ float4 lwi[64 * 17];
  __shared__ float4 xs[3][TR * 16];
  int tid = threadIdx.x;
  const float4* gws = (const float4*)WS;
  const float4* gwo = (const float4*)WO;
  const float4* gwi = (const float4*)WI;
  for (int i = tid; i < 1024; i += 256) {
    int dd = i >> 4, k4 = i & 15;
    lws[dd * 17 + k4] = gws[i];
    lwo[dd * 17 + k4] = gwo[i];
    lwi[dd * 17 + k4] = gwi[i];
  }
  int lane = tid & 63;
  int wv = tid >> 6;
  const float4* hr4 = (const float4*)hr_self;

  for (int tile = blockIdx.x; tile < ntiles; tile += gridDim.x) {
    int row0 = tile * TR;
    __syncthreads();   // waves done reading xs (and, 1st iter, W staged)
    for (int i = tid; i < TR * 16; i += 256) {
      int r = i >> 4, k4 = i & 15;
      int row = row0 + r;
      if (row < N) {
        size_t base = (size_t)row * 16 + k4;   // float4 index
        float4 xh = ((const float4*)h_in)[base];
        float4 hs = hr4[k4];
        xh.x -= hs.x; xh.y -= hs.y; xh.z -= hs.z; xh.w -= hs.w;
        xs[0][i] = xh;
        xs[1][i] = ((const float4*)aggO)[base];
        xs[2][i] = ((const float4*)aggI)[base];
      }
    }
    __syncthreads();
    float acc[8];
#pragma unroll
    for (int r = 0; r < 8; ++r) acc[r] = 0.f;
    for (int k4 = 0; k4 < 16; ++k4) {
      float4 ws4 = lws[lane * 17 + k4];
      float4 wo4 = lwo[lane * 17 + k4];
      float4 wi4 = lwi[lane * 17 + k4];
#pragma unroll
      for (int r = 0; r < 8; ++r) {
        int lr = (wv * 8 + r) * 16 + k4;
        float4 xh = xs[0][lr];
        float4 xo = xs[1][lr];
        float4 xi = xs[2][lr];
        acc[r] += xh.x * ws4.x + xh.y * ws4.y + xh.z * ws4.z + xh.w * ws4.w +
                  xo.x * wo4.x + xo.y * wo4.y + xo.z * wo4.z + xo.w * wo4.w +
                  xi.x * wi4.x + xi.y * wi4.y + xi.z * wi4.z + xi.w * wi4.w;
      }
    }
#pragma unroll
    for (int r = 0; r < 8; ++r) {
      int row = row0 + wv * 8 + r;
      if (row < N) {
        float v = acc[r];
        if (do_relu) v = fmaxf(v, 0.f);
        h_out[(size_t)row * D + lane] = v;
      }
    }
  }
}

extern "C" void kernel_launch(void* const* d_in, const int* in_sizes, int n_in,
                              void* d_out, int out_size, void* d_ws, size_t ws_size,
                              hipStream_t stream) {
  const float* h_u   = (const float*)d_in[0];
  const float* Basis = (const float*)d_in[1];
  const float* alpha = (const float*)d_in[2];
  const float* W_O   = (const float*)d_in[3];
  const float* W_I   = (const float*)d_in[4];
  const float* W_S   = (const float*)d_in[5];
  const float* W_rel = (const float*)d_in[6];
  const int* src  = (const int*)d_in[7];
  const int* dst  = (const int*)d_in[8];
  const int* et   = (const int*)d_in[9];
  const int* edir = (const int*)d_in[10];
  int N = in_sizes[0] / D;
  int E = in_sizes[7];
  int NB = (N + BNODES - 1) >> BSH;     // 782 for N=100000 (must be <= 1024)

  char* ws = (char*)d_ws;
  size_t off = 0;
  auto alloc = [&](size_t bytes) -> void* {
    void* p = ws + off;
    off = (off + bytes + 255) & ~(size_t)255;
    return p;
  };
  float* h_buf = (float*)alloc((size_t)N * D * 4);
  float* aggO  = (float*)alloc((size_t)N * D * 4);
  float* aggI  = (float*)alloc((size_t)N * D * 4);
  float* hrA   = (float*)alloc(192 * 4);
  float* hrB   = (float*)alloc(192 * 4);
  int* startv  = (int*)alloc((size_t)(N + 1) * 4);
  int* perm    = (int*)alloc((size_t)E * 4);
  int* tmp     = (int*)alloc((size_t)E * 4);
  int* bcnt    = (int*)alloc((size_t)(NB + 1) * 4);
  int* bstart  = (int*)alloc((size_t)(NB + 1) * 4);
  int* bcursor = (int*)alloc((size_t)(NB + 1) * 4);

  // ---- two-level bucket CSR build (once per launch) ----
  hipMemsetAsync(bcnt, 0, (size_t)NB * 4, stream);
  int eb = (E + 255) / 256;
  bucket_hist<<<eb, 256, 0, stream>>>(dst, bcnt, E);
  bucket_scan<<<1, 1024, 0, stream>>>(bcnt, bstart, bcursor, NB);
  bucket_scatter<<<eb, 256, 0, stream>>>(src, dst, et, edir, bcursor, tmp, E);
  bucket_finalize<<<NB, 256, 0, stream>>>(tmp, bstart, startv, perm, N, NB);

  hr_init_kernel<<<1, 192, 0, stream>>>(alpha, Basis, hrA);

  float* hr_cur = hrA;
  float* hr_nxt = hrB;
  int nb_g = (N + 3) / 4;
  int ntiles = (N + TR - 1) / TR;       // 3125
  int nb_n = ntiles < 1024 ? ntiles : 1024;
  for (int l = 0; l < NLAYERS; ++l) {
    const float* h_src = (l == 0) ? h_u : h_buf;
    gather_kernel<<<nb_g, 256, 0, stream>>>(h_src, hr_cur, startv, perm, aggO, aggI, N);
    float* outp = (l == NLAYERS - 1) ? (float*)d_out : h_buf;
    node_kernel<<<nb_n, 256, 0, stream>>>(
        h_src, aggO, aggI,
        W_S + (size_t)l * D * D, W_O + (size_t)l * D * D, W_I + (size_t)l * D * D,
        hr_cur + 2 * D, outp, (l < NLAYERS - 1) ? 1 : 0, N, ntiles);
    if (l < NLAYERS - 1) {
      hr_update_kernel<<<1, 192, 0, stream>>>(hr_cur, W_rel + (size_t)l * D * D, hr_nxt, 1);
      float* t = hr_cur; hr_cur = hr_nxt; hr_nxt = t;
    }
  }
}

// Round 8
// 567.934 us; speedup vs baseline: 1.9156x; 1.9156x over previous
//
#include <hip/hip_runtime.h>

constexpr int D = 64;
constexpr int NREL = 2;
constexpr int NBASIS = 16;
constexpr int NLAYERS = 3;
constexpr int SCAN_CHUNK = 1024;    // elements per scan block (256 thr x 4)
constexpr int BSH = 9;              // bucket = dst >> 9 (512 nodes/bucket)
constexpr int BNODES = 1 << BSH;    // 512
constexpr int PB = 256;             // partition blocks (edge chunks)
constexpr int TR = 32;              // rows per node-kernel tile

// h_r = alpha @ Basis   -> hr[3][64]
__global__ void hr_init_kernel(const float* __restrict__ alpha,
                               const float* __restrict__ basis,
                               float* __restrict__ hr) {
  int t = threadIdx.x;            // 192 threads
  int r = t >> 6, d = t & 63;
  float s = 0.f;
  for (int b = 0; b < NBASIS; ++b) s += alpha[r * NBASIS + b] * basis[b * D + d];
  hr[r * D + d] = s;
}

// h_r = act(h_r @ W_rel.T)
__global__ void hr_update_kernel(const float* __restrict__ hr_in,
                                 const float* __restrict__ Wrel,
                                 float* __restrict__ hr_out, int do_relu) {
  int t = threadIdx.x;            // 192 threads
  int r = t >> 6, d = t & 63;
  float s = 0.f;
  for (int k = 0; k < D; ++k) s += hr_in[r * D + k] * Wrel[d * D + k];
  if (do_relu) s = fmaxf(s, 0.f);
  hr_out[r * D + d] = s;
}

// ---- deterministic block-partition CSR build (no global atomics) ----
// K1: per-block LDS histogram -> ghist[bucket*PB + blk] (bucket-major for scan)
__global__ __launch_bounds__(256) void part_hist(const int* __restrict__ dst,
                                                 int* __restrict__ ghist,
                                                 int E, int chunk, int NB) {
  __shared__ int lh[512];
  int blk = blockIdx.x, t = threadIdx.x;
  for (int i = t; i < NB; i += 256) lh[i] = 0;
  __syncthreads();
  int beg = blk * chunk;
  int end = beg + chunk < E ? beg + chunk : E;
  for (int j = beg + t; j < end; j += 256) atomicAdd(&lh[dst[j] >> BSH], 1);
  __syncthreads();
  for (int i = t; i < NB; i += 256) ghist[(size_t)i * PB + blk] = lh[i];
}

// ---- generic parallel 3-phase exclusive scan (M elements) ----
__global__ void scan_partial(const int* __restrict__ cnt, int* __restrict__ bsums, int M) {
  int t = threadIdx.x;
  int base = blockIdx.x * SCAN_CHUNK + t * 4;
  int s = 0;
  if (base + 3 < M) {
    int4 v = *(const int4*)(cnt + base);
    s = v.x + v.y + v.z + v.w;
  } else {
    for (int i = 0; i < 4; ++i) if (base + i < M) s += cnt[base + i];
  }
  for (int off = 32; off > 0; off >>= 1) s += __shfl_down(s, off, 64);
  __shared__ int ws[4];
  if ((t & 63) == 0) ws[t >> 6] = s;
  __syncthreads();
  if (t == 0) bsums[blockIdx.x] = ws[0] + ws[1] + ws[2] + ws[3];
}

__global__ void scan_bsums(const int* __restrict__ bsums, int* __restrict__ boffs,
                           int SB, int* __restrict__ totalp) {
  __shared__ int sh[128];
  int t = threadIdx.x;
  int v = (t < SB) ? bsums[t] : 0;
  sh[t] = v;
  __syncthreads();
  for (int off = 1; off < 128; off <<= 1) {
    int u = (t >= off) ? sh[t - off] : 0;
    __syncthreads();
    sh[t] += u;
    __syncthreads();
  }
  if (t < SB) boffs[t] = sh[t] - v;
  if (t == SB - 1) *totalp = sh[t];
}

__global__ void scan_final(const int* __restrict__ cnt, const int* __restrict__ boffs,
                           int* __restrict__ out, int M) {
  int t = threadIdx.x;
  int base = blockIdx.x * SCAN_CHUNK + t * 4;
  int v0 = 0, v1 = 0, v2 = 0, v3 = 0;
  if (base + 3 < M) {
    int4 v = *(const int4*)(cnt + base);
    v0 = v.x; v1 = v.y; v2 = v.z; v3 = v.w;
  } else {
    if (base + 0 < M) v0 = cnt[base + 0];
    if (base + 1 < M) v1 = cnt[base + 1];
    if (base + 2 < M) v2 = cnt[base + 2];
    if (base + 3 < M) v3 = cnt[base + 3];
  }
  int ts = v0 + v1 + v2 + v3;
  int lane = t & 63;
  int incl = ts;
  for (int off = 1; off < 64; off <<= 1) {
    int u = __shfl_up(incl, off, 64);
    if (lane >= off) incl += u;
  }
  __shared__ int wsum[4];
  if (lane == 63) wsum[t >> 6] = incl;
  __syncthreads();
  int woff = 0;
  for (int w = 0; w < (t >> 6); ++w) woff += wsum[w];
  int run = boffs[blockIdx.x] + woff + incl - ts;
  if (base + 0 < M) out[base + 0] = run;
  if (base + 1 < M) out[base + 1] = run + v0;
  if (base + 2 < M) out[base + 2] = run + v0 + v1;
  if (base + 3 < M) out[base + 3] = run + v0 + v1 + v2;
}

// K3: re-read chunk, LDS cursors seeded from scanned goffs, write tmp.
// payload: src[0:16] | et<<17 | dir<<18 | dstlow<<19
__global__ __launch_bounds__(256) void part_scatter(
    const int* __restrict__ src, const int* __restrict__ dst,
    const int* __restrict__ et, const int* __restrict__ dir,
    const int* __restrict__ goffs, int* __restrict__ tmp,
    int E, int chunk, int NB) {
  __shared__ int lc[512];
  int blk = blockIdx.x, t = threadIdx.x;
  for (int i = t; i < NB; i += 256) lc[i] = goffs[(size_t)i * PB + blk];
  __syncthreads();
  int beg = blk * chunk;
  int end = beg + chunk < E ? beg + chunk : E;
  for (int j = beg + t; j < end; j += 256) {
    int d = dst[j];
    int b = d >> BSH;
    int p = atomicAdd(&lc[b], 1);
    tmp[p] = src[j] | (et[j] << 17) | (dir[j] << 18) | ((d & (BNODES - 1)) << 19);
  }
}

// K4: one block per bucket (512 local nodes): LDS histogram + scan -> startv,
// then scatter perm into the bucket's contiguous region.
__global__ __launch_bounds__(256) void bucket_finalize(
    const int* __restrict__ tmp, const int* __restrict__ goffs,
    int* __restrict__ startv, int* __restrict__ perm, int N, int NB, int E) {
  __shared__ int lcnt[BNODES];
  __shared__ int lstart[BNODES];
  __shared__ int lcur[BNODES];
  __shared__ int spair[256];
  int b = blockIdx.x, t = threadIdx.x;
  int beg = goffs[(size_t)b * PB];
  int end = (b == NB - 1) ? E : goffs[(size_t)(b + 1) * PB];
  lcnt[t] = 0;
  lcnt[t + 256] = 0;
  __syncthreads();
  for (int j = beg + t; j < end; j += 256)
    atomicAdd(&lcnt[(tmp[j] >> 19) & (BNODES - 1)], 1);
  __syncthreads();
  int c0 = lcnt[2 * t], c1 = lcnt[2 * t + 1];
  spair[t] = c0 + c1;
  __syncthreads();
  for (int off = 1; off < 256; off <<= 1) {
    int u = (t >= off) ? spair[t - off] : 0;
    __syncthreads();
    spair[t] += u;
    __syncthreads();
  }
  int epair = spair[t] - (c0 + c1);   // exclusive prefix of pair
  lstart[2 * t] = epair;
  lstart[2 * t + 1] = epair + c0;
  lcur[2 * t] = epair;
  lcur[2 * t + 1] = epair + c0;
  int v0 = (b << BSH) + 2 * t;
  if (v0 < N) startv[v0] = beg + epair;
  if (v0 + 1 < N) startv[v0 + 1] = beg + epair + c0;
  if (b == NB - 1 && t == 0) startv[N] = E;
  __syncthreads();
  for (int j = beg + t; j < end; j += 256) {
    int w = tmp[j];
    int p = atomicAdd(&lcur[(w >> 19) & (BNODES - 1)], 1);
    perm[beg + p] = w & 0x7FFFF;
  }
}

// wave per node: aggO[v], aggI[v] = sum over in-edges of (h[src]-hr[et]) split by dir.
// Edges processed in masked groups of 8: 8 independent row loads in flight.
__global__ __launch_bounds__(256) void gather_kernel(
    const float* __restrict__ h, const float* __restrict__ hr,
    const int* __restrict__ start, const int* __restrict__ perm,
    float* __restrict__ aggO, float* __restrict__ aggI, int N) {
  int lane = threadIdx.x & 63;
  int v = blockIdx.x * 4 + (threadIdx.x >> 6);
  if (v >= N) return;
  float hr0 = hr[lane];
  float hr1 = hr[D + lane];
  int beg = start[v], end = start[v + 1];
  float accO = 0.f, accI = 0.f;
  for (int j = beg; j < end; j += 8) {
    int pp[8];
    float ff[8];
#pragma unroll
    for (int u = 0; u < 8; ++u) {
      int jj = j + u < end ? j + u : beg;   // OOB clamps to beg (cached)
      pp[u] = perm[jj];
    }
#pragma unroll
    for (int u = 0; u < 8; ++u)
      ff[u] = h[(size_t)(pp[u] & 0x1FFFF) * D + lane];
#pragma unroll
    for (int u = 0; u < 8; ++u) {
      if (j + u < end) {
        float c = ff[u] - (((pp[u] >> 17) & 1) ? hr1 : hr0);
        if (pp[u] & (1 << 18)) accI += c; else accO += c;
      }
    }
  }
  aggO[(size_t)v * D + lane] = accO;
  aggI[(size_t)v * D + lane] = accI;
}

// h_out[v] = act((h[v]-hr_self)@WS.T + aggO[v]@WO.T + aggI[v]@WI.T)
__global__ __launch_bounds__(256, 2) void node_kernel(
    const float* __restrict__ h_in, const float* __restrict__ aggO,
    const float* __restrict__ aggI, const float* __restrict__ WS,
    const float* __restrict__ WO, const float* __restrict__ WI,
    const float* __restrict__ hr_self, float* __restrict__ h_out,
    int do_relu, int N, int ntiles) {
  __shared__ float4 lws[64 * 17];
  __shared__ float4 lwo[64 * 17];
  __shared__ float4 lwi[64 * 17];
  __shared__ float4 xs[3][TR * 16];
  int tid = threadIdx.x;
  const float4* gws = (const float4*)WS;
  const float4* gwo = (const float4*)WO;
  const float4* gwi = (const float4*)WI;
  for (int i = tid; i < 1024; i += 256) {
    int dd = i >> 4, k4 = i & 15;
    lws[dd * 17 + k4] = gws[i];
    lwo[dd * 17 + k4] = gwo[i];
    lwi[dd * 17 + k4] = gwi[i];
  }
  int lane = tid & 63;
  int wv = tid >> 6;
  const float4* hr4 = (const float4*)hr_self;

  for (int tile = blockIdx.x; tile < ntiles; tile += gridDim.x) {
    int row0 = tile * TR;
    __syncthreads();
    for (int i = tid; i < TR * 16; i += 256) {
      int r = i >> 4, k4 = i & 15;
      int row = row0 + r;
      if (row < N) {
        size_t base = (size_t)row * 16 + k4;
        float4 xh = ((const float4*)h_in)[base];
        float4 hs = hr4[k4];
        xh.x -= hs.x; xh.y -= hs.y; xh.z -= hs.z; xh.w -= hs.w;
        xs[0][i] = xh;
        xs[1][i] = ((const float4*)aggO)[base];
        xs[2][i] = ((const float4*)aggI)[base];
      }
    }
    __syncthreads();
    float acc[8];
#pragma unroll
    for (int r = 0; r < 8; ++r) acc[r] = 0.f;
    for (int k4 = 0; k4 < 16; ++k4) {
      float4 ws4 = lws[lane * 17 + k4];
      float4 wo4 = lwo[lane * 17 + k4];
      float4 wi4 = lwi[lane * 17 + k4];
#pragma unroll
      for (int r = 0; r < 8; ++r) {
        int lr = (wv * 8 + r) * 16 + k4;
        float4 xh = xs[0][lr];
        float4 xo = xs[1][lr];
        float4 xi = xs[2][lr];
        acc[r] += xh.x * ws4.x + xh.y * ws4.y + xh.z * ws4.z + xh.w * ws4.w +
                  xo.x * wo4.x + xo.y * wo4.y + xo.z * wo4.z + xo.w * wo4.w +
                  xi.x * wi4.x + xi.y * wi4.y + xi.z * wi4.z + xi.w * wi4.w;
      }
    }
#pragma unroll
    for (int r = 0; r < 8; ++r) {
      int row = row0 + wv * 8 + r;
      if (row < N) {
        float v = acc[r];
        if (do_relu) v = fmaxf(v, 0.f);
        h_out[(size_t)row * D + lane] = v;
      }
    }
  }
}

extern "C" void kernel_launch(void* const* d_in, const int* in_sizes, int n_in,
                              void* d_out, int out_size, void* d_ws, size_t ws_size,
                              hipStream_t stream) {
  const float* h_u   = (const float*)d_in[0];
  const float* Basis = (const float*)d_in[1];
  const float* alpha = (const float*)d_in[2];
  const float* W_O   = (const float*)d_in[3];
  const float* W_I   = (const float*)d_in[4];
  const float* W_S   = (const float*)d_in[5];
  const float* W_rel = (const float*)d_in[6];
  const int* src  = (const int*)d_in[7];
  const int* dst  = (const int*)d_in[8];
  const int* et   = (const int*)d_in[9];
  const int* edir = (const int*)d_in[10];
  int N = in_sizes[0] / D;
  int E = in_sizes[7];
  int NB = (N + BNODES - 1) >> BSH;     // 196 for N=100000 (must be <= 512)
  int M = NB * PB;                      // ghist size (50176)
  int chunk = (E + PB - 1) / PB;        // 4688

  char* ws = (char*)d_ws;
  size_t off = 0;
  auto alloc = [&](size_t bytes) -> void* {
    void* p = ws + off;
    off = (off + bytes + 255) & ~(size_t)255;
    return p;
  };
  float* h_buf = (float*)alloc((size_t)N * D * 4);
  float* aggO  = (float*)alloc((size_t)N * D * 4);
  float* aggI  = (float*)alloc((size_t)N * D * 4);
  float* hrA   = (float*)alloc(192 * 4);
  float* hrB   = (float*)alloc(192 * 4);
  int* startv  = (int*)alloc((size_t)(N + 1) * 4);
  int* perm    = (int*)alloc((size_t)E * 4);
  int* tmp     = (int*)alloc((size_t)E * 4);
  int* ghist   = (int*)alloc((size_t)M * 4);
  int* goffs   = (int*)alloc((size_t)(M + 1) * 4);
  int SB = (M + SCAN_CHUNK - 1) / SCAN_CHUNK;    // 49 (<=128)
  int* bsums   = (int*)alloc((size_t)SB * 4);
  int* boffs   = (int*)alloc((size_t)SB * 4);

  // ---- CSR build (once per launch, no global atomics) ----
  part_hist<<<PB, 256, 0, stream>>>(dst, ghist, E, chunk, NB);
  scan_partial<<<SB, 256, 0, stream>>>(ghist, bsums, M);
  scan_bsums<<<1, 128, 0, stream>>>(bsums, boffs, SB, goffs + M);
  scan_final<<<SB, 256, 0, stream>>>(ghist, boffs, goffs, M);
  part_scatter<<<PB, 256, 0, stream>>>(src, dst, et, edir, goffs, tmp, E, chunk, NB);
  bucket_finalize<<<NB, 256, 0, stream>>>(tmp, goffs, startv, perm, N, NB, E);

  hr_init_kernel<<<1, 192, 0, stream>>>(alpha, Basis, hrA);

  float* hr_cur = hrA;
  float* hr_nxt = hrB;
  int nb_g = (N + 3) / 4;
  int ntiles = (N + TR - 1) / TR;
  int nb_n = ntiles < 1024 ? ntiles : 1024;
  for (int l = 0; l < NLAYERS; ++l) {
    const float* h_src = (l == 0) ? h_u : h_buf;
    gather_kernel<<<nb_g, 256, 0, stream>>>(h_src, hr_cur, startv, perm, aggO, aggI, N);
    float* outp = (l == NLAYERS - 1) ? (float*)d_out : h_buf;
    node_kernel<<<nb_n, 256, 0, stream>>>(
        h_src, aggO, aggI,
        W_S + (size_t)l * D * D, W_O + (size_t)l * D * D, W_I + (size_t)l * D * D,
        hr_cur + 2 * D, outp, (l < NLAYERS - 1) ? 1 : 0, N, ntiles);
    if (l < NLAYERS - 1) {
      hr_update_kernel<<<1, 192, 0, stream>>>(hr_cur, W_rel + (size_t)l * D * D, hr_nxt, 1);
      float* t = hr_cur; hr_cur = hr_nxt; hr_nxt = t;
    }
  }
}

// Round 10
// 567.373 us; speedup vs baseline: 1.9175x; 1.0010x over previous
//
#include <hip/hip_runtime.h>

constexpr int D = 64;
constexpr int NBASIS = 16;
constexpr int NLAYERS = 3;
constexpr int SCAN_CHUNK = 1024;    // elements per scan block (256 thr x 4)
constexpr int BSH = 9;              // bucket = dst >> 9 (512 nodes/bucket)
constexpr int BNODES = 1 << BSH;    // 512
constexpr int PB = 256;             // partition blocks (edge chunks)
constexpr int NR = 128;             // rows per node-GEMM block

// hr for ALL layers upfront: hr[l][3][64], l=0..2
__global__ void hr_all_kernel(const float* __restrict__ alpha,
                              const float* __restrict__ basis,
                              const float* __restrict__ Wrel,
                              float* __restrict__ hr) {
  __shared__ float cur[192], nxt[192];
  int t = threadIdx.x;             // 192 threads
  int r = t >> 6, d = t & 63;
  float s = 0.f;
  for (int b = 0; b < NBASIS; ++b) s += alpha[r * NBASIS + b] * basis[b * D + d];
  cur[t] = s;
  hr[t] = s;
  __syncthreads();
  for (int l = 0; l < NLAYERS - 1; ++l) {
    float v = 0.f;
    for (int k = 0; k < D; ++k) v += cur[r * D + k] * Wrel[l * D * D + d * D + k];
    v = fmaxf(v, 0.f);
    nxt[t] = v;
    hr[(l + 1) * 192 + t] = v;
    __syncthreads();
    cur[t] = nxt[t];
    __syncthreads();
  }
}

// ---- deterministic block-partition CSR build (no global atomics) ----
__global__ __launch_bounds__(256) void part_hist(const int* __restrict__ dst,
                                                 int* __restrict__ ghist,
                                                 int E, int chunk, int NB) {
  __shared__ int lh[512];
  int blk = blockIdx.x, t = threadIdx.x;
  for (int i = t; i < NB; i += 256) lh[i] = 0;
  __syncthreads();
  int beg = blk * chunk;
  int end = beg + chunk < E ? beg + chunk : E;
  for (int j = beg + t; j < end; j += 256) atomicAdd(&lh[dst[j] >> BSH], 1);
  __syncthreads();
  for (int i = t; i < NB; i += 256) ghist[(size_t)i * PB + blk] = lh[i];
}

__global__ void scan_partial(const int* __restrict__ cnt, int* __restrict__ bsums, int M) {
  int t = threadIdx.x;
  int base = blockIdx.x * SCAN_CHUNK + t * 4;
  int s = 0;
  if (base + 3 < M) {
    int4 v = *(const int4*)(cnt + base);
    s = v.x + v.y + v.z + v.w;
  } else {
    for (int i = 0; i < 4; ++i) if (base + i < M) s += cnt[base + i];
  }
  for (int off = 32; off > 0; off >>= 1) s += __shfl_down(s, off, 64);
  __shared__ int ws[4];
  if ((t & 63) == 0) ws[t >> 6] = s;
  __syncthreads();
  if (t == 0) bsums[blockIdx.x] = ws[0] + ws[1] + ws[2] + ws[3];
}

__global__ void scan_bsums(const int* __restrict__ bsums, int* __restrict__ boffs,
                           int SB, int* __restrict__ totalp) {
  __shared__ int sh[128];
  int t = threadIdx.x;
  int v = (t < SB) ? bsums[t] : 0;
  sh[t] = v;
  __syncthreads();
  for (int off = 1; off < 128; off <<= 1) {
    int u = (t >= off) ? sh[t - off] : 0;
    __syncthreads();
    sh[t] += u;
    __syncthreads();
  }
  if (t < SB) boffs[t] = sh[t] - v;
  if (t == SB - 1) *totalp = sh[t];
}

__global__ void scan_final(const int* __restrict__ cnt, const int* __restrict__ boffs,
                           int* __restrict__ out, int M) {
  int t = threadIdx.x;
  int base = blockIdx.x * SCAN_CHUNK + t * 4;
  int v0 = 0, v1 = 0, v2 = 0, v3 = 0;
  if (base + 3 < M) {
    int4 v = *(const int4*)(cnt + base);
    v0 = v.x; v1 = v.y; v2 = v.z; v3 = v.w;
  } else {
    if (base + 0 < M) v0 = cnt[base + 0];
    if (base + 1 < M) v1 = cnt[base + 1];
    if (base + 2 < M) v2 = cnt[base + 2];
    if (base + 3 < M) v3 = cnt[base + 3];
  }
  int ts = v0 + v1 + v2 + v3;
  int lane = t & 63;
  int incl = ts;
  for (int off = 1; off < 64; off <<= 1) {
    int u = __shfl_up(incl, off, 64);
    if (lane >= off) incl += u;
  }
  __shared__ int wsum[4];
  if (lane == 63) wsum[t >> 6] = incl;
  __syncthreads();
  int woff = 0;
  for (int w = 0; w < (t >> 6); ++w) woff += wsum[w];
  int run = boffs[blockIdx.x] + woff + incl - ts;
  if (base + 0 < M) out[base + 0] = run;
  if (base + 1 < M) out[base + 1] = run + v0;
  if (base + 2 < M) out[base + 2] = run + v0 + v1;
  if (base + 3 < M) out[base + 3] = run + v0 + v1 + v2;
}

__global__ __launch_bounds__(256) void part_scatter(
    const int* __restrict__ src, const int* __restrict__ dst,
    const int* __restrict__ et, const int* __restrict__ dir,
    const int* __restrict__ goffs, int* __restrict__ tmp,
    int E, int chunk, int NB) {
  __shared__ int lc[512];
  int blk = blockIdx.x, t = threadIdx.x;
  for (int i = t; i < NB; i += 256) lc[i] = goffs[(size_t)i * PB + blk];
  __syncthreads();
  int beg = blk * chunk;
  int end = beg + chunk < E ? beg + chunk : E;
  for (int j = beg + t; j < end; j += 256) {
    int d = dst[j];
    int b = d >> BSH;
    int p = atomicAdd(&lc[b], 1);
    tmp[p] = src[j] | (et[j] << 17) | (dir[j] << 18) | ((d & (BNODES - 1)) << 19);
  }
}

__global__ __launch_bounds__(256) void bucket_finalize(
    const int* __restrict__ tmp, const int* __restrict__ goffs,
    int* __restrict__ startv, int* __restrict__ perm, int N, int NB, int E) {
  __shared__ int lcnt[BNODES];
  __shared__ int lcur[BNODES];
  __shared__ int spair[256];
  int b = blockIdx.x, t = threadIdx.x;
  int beg = goffs[(size_t)b * PB];
  int end = (b == NB - 1) ? E : goffs[(size_t)(b + 1) * PB];
  lcnt[t] = 0;
  lcnt[t + 256] = 0;
  __syncthreads();
  for (int j = beg + t; j < end; j += 256)
    atomicAdd(&lcnt[(tmp[j] >> 19) & (BNODES - 1)], 1);
  __syncthreads();
  int c0 = lcnt[2 * t], c1 = lcnt[2 * t + 1];
  spair[t] = c0 + c1;
  __syncthreads();
  for (int off = 1; off < 256; off <<= 1) {
    int u = (t >= off) ? spair[t - off] : 0;
    __syncthreads();
    spair[t] += u;
    __syncthreads();
  }
  int epair = spair[t] - (c0 + c1);
  lcur[2 * t] = epair;
  lcur[2 * t + 1] = epair + c0;
  int v0 = (b << BSH) + 2 * t;
  if (v0 < N) startv[v0] = beg + epair;
  if (v0 + 1 < N) startv[v0 + 1] = beg + epair + c0;
  if (b == NB - 1 && t == 0) startv[N] = E;
  __syncthreads();
  for (int j = beg + t; j < end; j += 256) {
    int w = tmp[j];
    int p = atomicAdd(&lcur[(w >> 19) & (BNODES - 1)], 1);
    perm[beg + p] = w & 0x7FFFF;
  }
}

// wave per node: 8-deep MLP edge gather
__global__ __launch_bounds__(256) void gather_kernel(
    const float* __restrict__ h, const float* __restrict__ hr,
    const int* __restrict__ start, const int* __restrict__ perm,
    float* __restrict__ aggO, float* __restrict__ aggI, int N) {
  int lane = threadIdx.x & 63;
  int v = blockIdx.x * 4 + (threadIdx.x >> 6);
  if (v >= N) return;
  float hr0 = hr[lane];
  float hr1 = hr[D + lane];
  int beg = start[v], end = start[v + 1];
  float accO = 0.f, accI = 0.f;
  for (int j = beg; j < end; j += 8) {
    int pp[8];
    float ff[8];
#pragma unroll
    for (int u = 0; u < 8; ++u) {
      int jj = j + u < end ? j + u : beg;
      pp[u] = perm[jj];
    }
#pragma unroll
    for (int u = 0; u < 8; ++u)
      ff[u] = h[(size_t)(pp[u] & 0x1FFFF) * D + lane];
#pragma unroll
    for (int u = 0; u < 8; ++u) {
      if (j + u < end) {
        float c = ff[u] - (((pp[u] >> 17) & 1) ? hr1 : hr0);
        if (pp[u] & (1 << 18)) accI += c; else accO += c;
      }
    }
  }
  aggO[(size_t)v * D + lane] = accO;
  aggI[(size_t)v * D + lane] = accI;
}

// node GEMM: h_out[row][d] = act( (h-hr_s)[row]·WS[d] + aggO[row]·WO[d] + aggI[row]·WI[d] )
// 128 rows x 64 cols per block, 512 threads, 4x4 register tile per thread.
// x and W row-major in LDS with pad 65 (all reads <=2-way or broadcast: free).
__global__ __launch_bounds__(512) void node_gemm(
    const float* __restrict__ h_in, const float* __restrict__ aggO,
    const float* __restrict__ aggI, const float* __restrict__ WS,
    const float* __restrict__ WO, const float* __restrict__ WI,
    const float* __restrict__ hr_self, float* __restrict__ h_out,
    int do_relu, int N) {
  __shared__ float xh[NR][65], xo[NR][65], xi[NR][65];
  __shared__ float ws_[64][65], wo_[64][65], wi_[64][65];
  int tid = threadIdx.x;
  int row0 = blockIdx.x * NR;
  // stage W: 1024 float4 per mat
  for (int idx = tid; idx < 1024; idx += 512) {
    int d = idx >> 4, k0 = (idx & 15) * 4;
    float4 a = ((const float4*)WS)[idx];
    float4 b = ((const float4*)WO)[idx];
    float4 c = ((const float4*)WI)[idx];
    ws_[d][k0] = a.x; ws_[d][k0+1] = a.y; ws_[d][k0+2] = a.z; ws_[d][k0+3] = a.w;
    wo_[d][k0] = b.x; wo_[d][k0+1] = b.y; wo_[d][k0+2] = b.z; wo_[d][k0+3] = b.w;
    wi_[d][k0] = c.x; wi_[d][k0+1] = c.y; wi_[d][k0+2] = c.z; wi_[d][k0+3] = c.w;
  }
  // stage x: NR*16 float4 per mat (coalesced reads, -hr fused into xh)
  const float4* hr4 = (const float4*)hr_self;
  for (int idx = tid; idx < NR * 16; idx += 512) {
    int r = idx >> 4, kq = idx & 15, k0 = kq * 4;
    int row = row0 + r;
    float4 a = make_float4(0.f, 0.f, 0.f, 0.f), b = a, c = a;
    if (row < N) {
      size_t g = (size_t)row * 16 + kq;
      a = ((const float4*)h_in)[g];
      float4 hs = hr4[kq];
      a.x -= hs.x; a.y -= hs.y; a.z -= hs.z; a.w -= hs.w;
      b = ((const float4*)aggO)[g];
      c = ((const float4*)aggI)[g];
    }
    xh[r][k0] = a.x; xh[r][k0+1] = a.y; xh[r][k0+2] = a.z; xh[r][k0+3] = a.w;
    xo[r][k0] = b.x; xo[r][k0+1] = b.y; xo[r][k0+2] = b.z; xo[r][k0+3] = b.w;
    xi[r][k0] = c.x; xi[r][k0+1] = c.y; xi[r][k0+2] = c.z; xi[r][k0+3] = c.w;
  }
  __syncthreads();
  int tc4 = (tid & 15) * 4;
  int tr4 = (tid >> 4) * 4;
  float acc[4][4] = {{0.f}};
#define GEMM1(X, W)                                                          \
  _Pragma("unroll 4")                                                        \
  for (int k = 0; k < 64; ++k) {                                             \
    float x0 = X[tr4+0][k], x1 = X[tr4+1][k], x2 = X[tr4+2][k], x3 = X[tr4+3][k]; \
    float w0 = W[tc4+0][k], w1 = W[tc4+1][k], w2 = W[tc4+2][k], w3 = W[tc4+3][k]; \
    acc[0][0]+=x0*w0; acc[0][1]+=x0*w1; acc[0][2]+=x0*w2; acc[0][3]+=x0*w3;  \
    acc[1][0]+=x1*w0; acc[1][1]+=x1*w1; acc[1][2]+=x1*w2; acc[1][3]+=x1*w3;  \
    acc[2][0]+=x2*w0; acc[2][1]+=x2*w1; acc[2][2]+=x2*w2; acc[2][3]+=x2*w3;  \
    acc[3][0]+=x3*w0; acc[3][1]+=x3*w1; acc[3][2]+=x3*w2; acc[3][3]+=x3*w3;  \
  }
  GEMM1(xh, ws_)
  GEMM1(xo, wo_)
  GEMM1(xi, wi_)
#undef GEMM1
#pragma unroll
  for (int i = 0; i < 4; ++i) {
    int row = row0 + tr4 + i;
    if (row < N) {
      float4 o = make_float4(acc[i][0], acc[i][1], acc[i][2], acc[i][3]);
      if (do_relu) {
        o.x = fmaxf(o.x, 0.f); o.y = fmaxf(o.y, 0.f);
        o.z = fmaxf(o.z, 0.f); o.w = fmaxf(o.w, 0.f);
      }
      ((float4*)h_out)[(size_t)row * 16 + (tc4 >> 2)] = o;
    }
  }
}

extern "C" void kernel_launch(void* const* d_in, const int* in_sizes, int n_in,
                              void* d_out, int out_size, void* d_ws, size_t ws_size,
                              hipStream_t stream) {
  const float* h_u   = (const float*)d_in[0];
  const float* Basis = (const float*)d_in[1];
  const float* alpha = (const float*)d_in[2];
  const float* W_O   = (const float*)d_in[3];
  const float* W_I   = (const float*)d_in[4];
  const float* W_S   = (const float*)d_in[5];
  const float* W_rel = (const float*)d_in[6];
  const int* src  = (const int*)d_in[7];
  const int* dst  = (const int*)d_in[8];
  const int* et   = (const int*)d_in[9];
  const int* edir = (const int*)d_in[10];
  int N = in_sizes[0] / D;
  int E = in_sizes[7];
  int NB = (N + BNODES - 1) >> BSH;     // 196 for N=100000
  int M = NB * PB;                      // 50176
  int chunk = (E + PB - 1) / PB;        // 4688

  char* ws = (char*)d_ws;
  size_t off = 0;
  auto alloc = [&](size_t bytes) -> void* {
    void* p = ws + off;
    off = (off + bytes + 255) & ~(size_t)255;
    return p;
  };
  float* h_buf = (float*)alloc((size_t)N * D * 4);
  float* aggO  = (float*)alloc((size_t)N * D * 4);
  float* aggI  = (float*)alloc((size_t)N * D * 4);
  float* hrbuf = (float*)alloc(3 * 192 * 4);
  int* startv  = (int*)alloc((size_t)(N + 1) * 4);
  int* perm    = (int*)alloc((size_t)E * 4);
  int* tmp     = (int*)alloc((size_t)E * 4);
  int* ghist   = (int*)alloc((size_t)M * 4);
  int* goffs   = (int*)alloc((size_t)(M + 1) * 4);
  int SB = (M + SCAN_CHUNK - 1) / SCAN_CHUNK;    // 49
  int* bsums   = (int*)alloc((size_t)SB * 4);
  int* boffs   = (int*)alloc((size_t)SB * 4);

  // ---- CSR build (once per launch, no global atomics) ----
  part_hist<<<PB, 256, 0, stream>>>(dst, ghist, E, chunk, NB);
  scan_partial<<<SB, 256, 0, stream>>>(ghist, bsums, M);
  scan_bsums<<<1, 128, 0, stream>>>(bsums, boffs, SB, goffs + M);
  scan_final<<<SB, 256, 0, stream>>>(ghist, boffs, goffs, M);
  part_scatter<<<PB, 256, 0, stream>>>(src, dst, et, edir, goffs, tmp, E, chunk, NB);
  bucket_finalize<<<NB, 256, 0, stream>>>(tmp, goffs, startv, perm, N, NB, E);

  hr_all_kernel<<<1, 192, 0, stream>>>(alpha, Basis, W_rel, hrbuf);

  int nb_g = (N + 3) / 4;
  int nb_n = (N + NR - 1) / NR;          // 782
  for (int l = 0; l < NLAYERS; ++l) {
    const float* h_src = (l == 0) ? h_u : h_buf;
    const float* hr_l = hrbuf + l * 192;
    gather_kernel<<<nb_g, 256, 0, stream>>>(h_src, hr_l, startv, perm, aggO, aggI, N);
    float* outp = (l == NLAYERS - 1) ? (float*)d_out : h_buf;
    node_gemm<<<nb_n, 512, 0, stream>>>(
        h_src, aggO, aggI,
        W_S + (size_t)l * D * D, W_O + (size_t)l * D * D, W_I + (size_t)l * D * D,
        hr_l + 2 * D, outp, (l < NLAYERS - 1) ? 1 : 0, N);
  }
}

// Round 12
// 505.986 us; speedup vs baseline: 2.1502x; 1.1213x over previous
//
#include <hip/hip_runtime.h>

constexpr int D = 64;
constexpr int NBASIS = 16;
constexpr int NLAYERS = 3;
constexpr int SCAN_CHUNK = 1024;    // elements per scan block (256 thr x 4)
constexpr int BSH = 9;              // bucket = dst >> 9 (512 nodes/bucket)
constexpr int BNODES = 1 << BSH;    // 512
constexpr int PB = 256;             // partition blocks (edge chunks)
constexpr int NR = 128;             // rows per node-GEMM block

// hr for ALL layers upfront: hr[l][3][64], l=0..2
__global__ void hr_all_kernel(const float* __restrict__ alpha,
                              const float* __restrict__ basis,
                              const float* __restrict__ Wrel,
                              float* __restrict__ hr) {
  __shared__ float cur[192], nxt[192];
  int t = threadIdx.x;             // 192 threads
  int r = t >> 6, d = t & 63;
  float s = 0.f;
  for (int b = 0; b < NBASIS; ++b) s += alpha[r * NBASIS + b] * basis[b * D + d];
  cur[t] = s;
  hr[t] = s;
  __syncthreads();
  for (int l = 0; l < NLAYERS - 1; ++l) {
    float v = 0.f;
    for (int k = 0; k < D; ++k) v += cur[r * D + k] * Wrel[l * D * D + d * D + k];
    v = fmaxf(v, 0.f);
    nxt[t] = v;
    hr[(l + 1) * 192 + t] = v;
    __syncthreads();
    cur[t] = nxt[t];
    __syncthreads();
  }
}

// ---- deterministic block-partition CSR build (no global atomics) ----
__global__ __launch_bounds__(256) void part_hist(const int* __restrict__ dst,
                                                 int* __restrict__ ghist,
                                                 int E, int chunk, int NB) {
  __shared__ int lh[512];
  int blk = blockIdx.x, t = threadIdx.x;
  for (int i = t; i < NB; i += 256) lh[i] = 0;
  __syncthreads();
  int beg = blk * chunk;
  int end = beg + chunk < E ? beg + chunk : E;
  for (int j = beg + t; j < end; j += 256) atomicAdd(&lh[dst[j] >> BSH], 1);
  __syncthreads();
  for (int i = t; i < NB; i += 256) ghist[(size_t)i * PB + blk] = lh[i];
}

__global__ void scan_partial(const int* __restrict__ cnt, int* __restrict__ bsums, int M) {
  int t = threadIdx.x;
  int base = blockIdx.x * SCAN_CHUNK + t * 4;
  int s = 0;
  if (base + 3 < M) {
    int4 v = *(const int4*)(cnt + base);
    s = v.x + v.y + v.z + v.w;
  } else {
    for (int i = 0; i < 4; ++i) if (base + i < M) s += cnt[base + i];
  }
  for (int off = 32; off > 0; off >>= 1) s += __shfl_down(s, off, 64);
  __shared__ int ws[4];
  if ((t & 63) == 0) ws[t >> 6] = s;
  __syncthreads();
  if (t == 0) bsums[blockIdx.x] = ws[0] + ws[1] + ws[2] + ws[3];
}

__global__ void scan_bsums(const int* __restrict__ bsums, int* __restrict__ boffs,
                           int SB, int* __restrict__ totalp) {
  __shared__ int sh[128];
  int t = threadIdx.x;
  int v = (t < SB) ? bsums[t] : 0;
  sh[t] = v;
  __syncthreads();
  for (int off = 1; off < 128; off <<= 1) {
    int u = (t >= off) ? sh[t - off] : 0;
    __syncthreads();
    sh[t] += u;
    __syncthreads();
  }
  if (t < SB) boffs[t] = sh[t] - v;
  if (t == SB - 1) *totalp = sh[t];
}

__global__ void scan_final(const int* __restrict__ cnt, const int* __restrict__ boffs,
                           int* __restrict__ out, int M) {
  int t = threadIdx.x;
  int base = blockIdx.x * SCAN_CHUNK + t * 4;
  int v0 = 0, v1 = 0, v2 = 0, v3 = 0;
  if (base + 3 < M) {
    int4 v = *(const int4*)(cnt + base);
    v0 = v.x; v1 = v.y; v2 = v.z; v3 = v.w;
  } else {
    if (base + 0 < M) v0 = cnt[base + 0];
    if (base + 1 < M) v1 = cnt[base + 1];
    if (base + 2 < M) v2 = cnt[base + 2];
    if (base + 3 < M) v3 = cnt[base + 3];
  }
  int ts = v0 + v1 + v2 + v3;
  int lane = t & 63;
  int incl = ts;
  for (int off = 1; off < 64; off <<= 1) {
    int u = __shfl_up(incl, off, 64);
    if (lane >= off) incl += u;
  }
  __shared__ int wsum[4];
  if (lane == 63) wsum[t >> 6] = incl;
  __syncthreads();
  int woff = 0;
  for (int w = 0; w < (t >> 6); ++w) woff += wsum[w];
  int run = boffs[blockIdx.x] + woff + incl - ts;
  if (base + 0 < M) out[base + 0] = run;
  if (base + 1 < M) out[base + 1] = run + v0;
  if (base + 2 < M) out[base + 2] = run + v0 + v1;
  if (base + 3 < M) out[base + 3] = run + v0 + v1 + v2;
}

__global__ __launch_bounds__(256) void part_scatter(
    const int* __restrict__ src, const int* __restrict__ dst,
    const int* __restrict__ et, const int* __restrict__ dir,
    const int* __restrict__ goffs, int* __restrict__ tmp,
    int E, int chunk, int NB) {
  __shared__ int lc[512];
  int blk = blockIdx.x, t = threadIdx.x;
  for (int i = t; i < NB; i += 256) lc[i] = goffs[(size_t)i * PB + blk];
  __syncthreads();
  int beg = blk * chunk;
  int end = beg + chunk < E ? beg + chunk : E;
  for (int j = beg + t; j < end; j += 256) {
    int d = dst[j];
    int b = d >> BSH;
    int p = atomicAdd(&lc[b], 1);
    tmp[p] = src[j] | (et[j] << 17) | (dir[j] << 18) | ((d & (BNODES - 1)) << 19);
  }
}

__global__ __launch_bounds__(256) void bucket_finalize(
    const int* __restrict__ tmp, const int* __restrict__ goffs,
    int* __restrict__ startv, int* __restrict__ perm, int N, int NB, int E) {
  __shared__ int lcnt[BNODES];
  __shared__ int lcur[BNODES];
  __shared__ int spair[256];
  int b = blockIdx.x, t = threadIdx.x;
  int beg = goffs[(size_t)b * PB];
  int end = (b == NB - 1) ? E : goffs[(size_t)(b + 1) * PB];
  lcnt[t] = 0;
  lcnt[t + 256] = 0;
  __syncthreads();
  for (int j = beg + t; j < end; j += 256)
    atomicAdd(&lcnt[(tmp[j] >> 19) & (BNODES - 1)], 1);
  __syncthreads();
  int c0 = lcnt[2 * t], c1 = lcnt[2 * t + 1];
  spair[t] = c0 + c1;
  __syncthreads();
  for (int off = 1; off < 256; off <<= 1) {
    int u = (t >= off) ? spair[t - off] : 0;
    __syncthreads();
    spair[t] += u;
    __syncthreads();
  }
  int epair = spair[t] - (c0 + c1);
  lcur[2 * t] = epair;
  lcur[2 * t + 1] = epair + c0;
  int v0 = (b << BSH) + 2 * t;
  if (v0 < N) startv[v0] = beg + epair;
  if (v0 + 1 < N) startv[v0 + 1] = beg + epair + c0;
  if (b == NB - 1 && t == 0) startv[N] = E;
  __syncthreads();
  for (int j = beg + t; j < end; j += 256) {
    int w = tmp[j];
    int p = atomicAdd(&lcur[(w >> 19) & (BNODES - 1)], 1);
    perm[beg + p] = w & 0x7FFFF;
  }
}

// wave per node: 8-deep MLP edge gather
__global__ __launch_bounds__(256) void gather_kernel(
    const float* __restrict__ h, const float* __restrict__ hr,
    const int* __restrict__ start, const int* __restrict__ perm,
    float* __restrict__ aggO, float* __restrict__ aggI, int N) {
  int lane = threadIdx.x & 63;
  int v = blockIdx.x * 4 + (threadIdx.x >> 6);
  if (v >= N) return;
  float hr0 = hr[lane];
  float hr1 = hr[D + lane];
  int beg = start[v], end = start[v + 1];
  float accO = 0.f, accI = 0.f;
  for (int j = beg; j < end; j += 8) {
    int pp[8];
    float ff[8];
#pragma unroll
    for (int u = 0; u < 8; ++u) {
      int jj = j + u < end ? j + u : beg;
      pp[u] = perm[jj];
    }
#pragma unroll
    for (int u = 0; u < 8; ++u)
      ff[u] = h[(size_t)(pp[u] & 0x1FFFF) * D + lane];
#pragma unroll
    for (int u = 0; u < 8; ++u) {
      if (j + u < end) {
        float c = ff[u] - (((pp[u] >> 17) & 1) ? hr1 : hr0);
        if (pp[u] & (1 << 18)) accI += c; else accO += c;
      }
    }
  }
  aggO[(size_t)v * D + lane] = accO;
  aggI[(size_t)v * D + lane] = accI;
}

// node GEMM v3: transposed-LDS, b128-only inner loop.
// Block: 128 rows x 64 cols, 256 threads. Thread tile: 8 rows (tr4 and tr4+64) x 4 cols.
// Per k per wave: 3 ds_read_b128 (24 LDS clk) feed 32 FMAs (64 VALU clk) -> VALU-bound.
// K chunked over the 3 matrices through one 50KB LDS buffer -> 3 blocks/CU.
__global__ __launch_bounds__(256) void node_gemm(
    const float* __restrict__ h_in, const float* __restrict__ aggO,
    const float* __restrict__ aggI, const float* __restrict__ WS,
    const float* __restrict__ WO, const float* __restrict__ WI,
    const float* __restrict__ hr_self, float* __restrict__ h_out,
    int do_relu, int N) {
  __shared__ float Xt[64][132];   // Xt[k][r], stride 132 (16B-aligned rows)
  __shared__ float Wt[64][68];    // Wt[k][c]
  int tid = threadIdx.x;
  int row0 = blockIdx.x * NR;
  int tr4 = (tid & 15) * 4;       // wave's 16 row-groups cover floats 0..63: 2-way = free
  int tc4 = (tid >> 4) * 4;
  const float4* hr4 = (const float4*)hr_self;
  const float* xsrc[3] = {h_in, aggO, aggI};
  const float* wsrc[3] = {WS, WO, WI};
  float acc[8][4];
#pragma unroll
  for (int i = 0; i < 8; ++i)
#pragma unroll
    for (int j = 0; j < 4; ++j) acc[i][j] = 0.f;

  for (int m = 0; m < 3; ++m) {
    // stage Wt (transpose): coalesced global float4 reads, scattered b32 LDS writes
    const float4* wp = (const float4*)wsrc[m];
    for (int idx = tid; idx < 1024; idx += 256) {
      int k4 = idx & 15, d = idx >> 4;
      float4 w = wp[d * 16 + k4];
      Wt[4 * k4 + 0][d] = w.x;
      Wt[4 * k4 + 1][d] = w.y;
      Wt[4 * k4 + 2][d] = w.z;
      Wt[4 * k4 + 3][d] = w.w;
    }
    // stage Xt (transpose, -hr_self fused for m==0)
    const float4* xp = (const float4*)xsrc[m];
    for (int idx = tid; idx < 2048; idx += 256) {
      int k4 = idx & 15, r = idx >> 4;
      int row = row0 + r;
      float4 a = make_float4(0.f, 0.f, 0.f, 0.f);
      if (row < N) {
        a = xp[(size_t)row * 16 + k4];
        if (m == 0) {
          float4 hs = hr4[k4];
          a.x -= hs.x; a.y -= hs.y; a.z -= hs.z; a.w -= hs.w;
        }
      }
      Xt[4 * k4 + 0][r] = a.x;
      Xt[4 * k4 + 1][r] = a.y;
      Xt[4 * k4 + 2][r] = a.z;
      Xt[4 * k4 + 3][r] = a.w;
    }
    __syncthreads();
#pragma unroll 2
    for (int k = 0; k < 64; ++k) {
      float4 xv0 = *(const float4*)&Xt[k][tr4];
      float4 xv1 = *(const float4*)&Xt[k][tr4 + 64];
      float4 wv  = *(const float4*)&Wt[k][tc4];
      float xr[8] = {xv0.x, xv0.y, xv0.z, xv0.w, xv1.x, xv1.y, xv1.z, xv1.w};
      float wr[4] = {wv.x, wv.y, wv.z, wv.w};
#pragma unroll
      for (int i = 0; i < 8; ++i)
#pragma unroll
        for (int j = 0; j < 4; ++j) acc[i][j] += xr[i] * wr[j];
    }
    __syncthreads();
  }
#pragma unroll
  for (int i = 0; i < 8; ++i) {
    int row = row0 + (i < 4 ? tr4 + i : 64 + tr4 + (i - 4));
    if (row < N) {
      float4 o = make_float4(acc[i][0], acc[i][1], acc[i][2], acc[i][3]);
      if (do_relu) {
        o.x = fmaxf(o.x, 0.f); o.y = fmaxf(o.y, 0.f);
        o.z = fmaxf(o.z, 0.f); o.w = fmaxf(o.w, 0.f);
      }
      ((float4*)h_out)[(size_t)row * 16 + (tc4 >> 2)] = o;
    }
  }
}

extern "C" void kernel_launch(void* const* d_in, const int* in_sizes, int n_in,
                              void* d_out, int out_size, void* d_ws, size_t ws_size,
                              hipStream_t stream) {
  const float* h_u   = (const float*)d_in[0];
  const float* Basis = (const float*)d_in[1];
  const float* alpha = (const float*)d_in[2];
  const float* W_O   = (const float*)d_in[3];
  const float* W_I   = (const float*)d_in[4];
  const float* W_S   = (const float*)d_in[5];
  const float* W_rel = (const float*)d_in[6];
  const int* src  = (const int*)d_in[7];
  const int* dst  = (const int*)d_in[8];
  const int* et   = (const int*)d_in[9];
  const int* edir = (const int*)d_in[10];
  int N = in_sizes[0] / D;
  int E = in_sizes[7];
  int NB = (N + BNODES - 1) >> BSH;     // 196 for N=100000
  int M = NB * PB;                      // 50176
  int chunk = (E + PB - 1) / PB;        // 4688

  char* ws = (char*)d_ws;
  size_t off = 0;
  auto alloc = [&](size_t bytes) -> void* {
    void* p = ws + off;
    off = (off + bytes + 255) & ~(size_t)255;
    return p;
  };
  float* h_buf = (float*)alloc((size_t)N * D * 4);
  float* aggO  = (float*)alloc((size_t)N * D * 4);
  float* aggI  = (float*)alloc((size_t)N * D * 4);
  float* hrbuf = (float*)alloc(3 * 192 * 4);
  int* startv  = (int*)alloc((size_t)(N + 1) * 4);
  int* perm    = (int*)alloc((size_t)E * 4);
  int* tmp     = (int*)alloc((size_t)E * 4);
  int* ghist   = (int*)alloc((size_t)M * 4);
  int* goffs   = (int*)alloc((size_t)(M + 1) * 4);
  int SB = (M + SCAN_CHUNK - 1) / SCAN_CHUNK;    // 49
  int* bsums   = (int*)alloc((size_t)SB * 4);
  int* boffs   = (int*)alloc((size_t)SB * 4);

  // ---- CSR build (once per launch, no global atomics) ----
  part_hist<<<PB, 256, 0, stream>>>(dst, ghist, E, chunk, NB);
  scan_partial<<<SB, 256, 0, stream>>>(ghist, bsums, M);
  scan_bsums<<<1, 128, 0, stream>>>(bsums, boffs, SB, goffs + M);
  scan_final<<<SB, 256, 0, stream>>>(ghist, boffs, goffs, M);
  part_scatter<<<PB, 256, 0, stream>>>(src, dst, et, edir, goffs, tmp, E, chunk, NB);
  bucket_finalize<<<NB, 256, 0, stream>>>(tmp, goffs, startv, perm, N, NB, E);

  hr_all_kernel<<<1, 192, 0, stream>>>(alpha, Basis, W_rel, hrbuf);

  int nb_g = (N + 3) / 4;
  int nb_n = (N + NR - 1) / NR;          // 782
  for (int l = 0; l < NLAYERS; ++l) {
    const float* h_src = (l == 0) ? h_u : h_buf;
    const float* hr_l = hrbuf + l * 192;
    gather_kernel<<<nb_g, 256, 0, stream>>>(h_src, hr_l, startv, perm, aggO, aggI, N);
    float* outp = (l == NLAYERS - 1) ? (float*)d_out : h_buf;
    node_gemm<<<nb_n, 256, 0, stream>>>(
        h_src, aggO, aggI,
        W_S + (size_t)l * D * D, W_O + (size_t)l * D * D, W_I + (size_t)l * D * D,
        hr_l + 2 * D, outp, (l < NLAYERS - 1) ? 1 : 0, N);
  }
}